// Round 1
// baseline (398.080 us; speedup 1.0000x reference)
//
#include <hip/hip_runtime.h>
#include <math.h>

#define NB 16
#define NCH 128
#define NH 64
#define NW 64
#define NP 1024

#define TN 32    // rows per block
#define TM 128   // m per chunk
#define KC 32    // k chunk
#define KP 36    // padded k stride in LDS

__device__ __forceinline__ float med3(float a, float b, float c) {
  return __builtin_amdgcn_fmed3f(a, b, c);
}

// ---------------- prep: normalize channel vectors, extract diag-pixel matrices ----------------
// V[b][c][n][ch], c=0 -> pixel (2nr,2nc), c=1 -> (2nr+1,2nc+1)
__global__ __launch_bounds__(256) void prep_kernel(const float* __restrict__ x,
                                                   float* __restrict__ V) {
  int blk = blockIdx.x;            // 0..127
  int t = threadIdx.x;             // 0..255
  int b = blk >> 3;
  int c = (blk >> 2) & 1;
  int n = (blk & 3) * 256 + t;
  int i = 2 * (n >> 5) + c;
  int j = 2 * (n & 31) + c;
  const float* xp = x + (size_t)b * NCH * NH * NW + i * NW + j;
  float ss = 0.f;
#pragma unroll 8
  for (int ch = 0; ch < NCH; ++ch) {
    float v = xp[(size_t)ch * NH * NW];
    ss += v * v;
  }
  float r = 1.0f / fmaxf(sqrtf(ss), 1e-12f);
  float* vp = V + (((size_t)b * 2 + c) * NP + n) * NCH;
#pragma unroll 8
  for (int ch = 0; ch < NCH; ++ch) {
    vp[ch] = xp[(size_t)ch * NH * NW] * r;
  }
}

// ---------------- corr passes ----------------
// PASS 1: rowsum[b][c][n] = sum_m exp(s_c[n,m])       (s symmetric -> col stats == row stats)
// PASS 2: A = exp(2s) * rinv_n * rinv_m ; keep top-3 per (row, channel); scatter to out pixels
template <int PASS>
__global__ __launch_bounds__(256, 2) void corr_kernel(
    const float* __restrict__ V, const float* __restrict__ alpha_p,
    float* __restrict__ rsum_g, float* __restrict__ out) {
  __shared__ __align__(16) float As[2][TN][KP];
  __shared__ __align__(16) float Bs[2][TM][KP];

  const int b = blockIdx.y;
  const int n0 = blockIdx.x * TN;
  const int t = threadIdx.x;
  const int tx = t & 31;   // m-slot: m = m0 + tx + 32*j
  const int ty = t >> 5;   // row group: rows n0 + ty*4 + i
  const float alpha = *alpha_p;
  const float* Vb = V + (size_t)b * 2 * NP * NCH;

  float sm[3][4];                    // pass 1: partial row sums
  float t0[3][4], t1[3][4], t2[3][4];// pass 2: top-3
  float rin[3][4];                   // pass 2: 1/S_n for own rows
#pragma unroll
  for (int c = 0; c < 3; ++c)
#pragma unroll
    for (int i = 0; i < 4; ++i) {
      sm[c][i] = 0.f;
      t0[c][i] = 0.f; t1[c][i] = 0.f; t2[c][i] = 0.f;
    }
  if (PASS == 2) {
#pragma unroll
    for (int c = 0; c < 3; ++c)
#pragma unroll
      for (int i = 0; i < 4; ++i) {
        int n = n0 + ty * 4 + i;
        rin[c][i] = 1.0f / rsum_g[((size_t)b * 3 + c) * NP + n];
      }
  }

  for (int mc = 0; mc < NP / TM; ++mc) {
    const int m0 = mc * TM;
    float acc[2][4][4];
#pragma unroll
    for (int c = 0; c < 2; ++c)
#pragma unroll
      for (int i = 0; i < 4; ++i)
#pragma unroll
        for (int j = 0; j < 4; ++j) acc[c][i][j] = 0.f;

    for (int k0 = 0; k0 < NCH; k0 += KC) {
      __syncthreads();
      // stage A tile: 2*TN*KC floats = 512 float4 -> 2 per thread
#pragma unroll
      for (int q = 0; q < 2; ++q) {
        int flat = q * 256 + t;
        int c = flat >> 8;
        int rem = flat & 255;
        int row = rem >> 3;
        int kg = rem & 7;
        float4 v4 = *(const float4*)(Vb + ((size_t)c * NP + n0 + row) * NCH + k0 + kg * 4);
        *(float4*)&As[c][row][kg * 4] = v4;
      }
      // stage B tile: 2*TM*KC floats = 2048 float4 -> 8 per thread
#pragma unroll
      for (int q = 0; q < 8; ++q) {
        int flat = q * 256 + t;
        int c = flat >> 10;
        int rem = flat & 1023;
        int row = rem >> 3;
        int kg = rem & 7;
        float4 v4 = *(const float4*)(Vb + ((size_t)c * NP + m0 + row) * NCH + k0 + kg * 4);
        *(float4*)&Bs[c][row][kg * 4] = v4;
      }
      __syncthreads();

      for (int kg = 0; kg < KC; kg += 4) {
        float4 a4[2][4], b4[2][4];
#pragma unroll
        for (int c = 0; c < 2; ++c)
#pragma unroll
          for (int i = 0; i < 4; ++i)
            a4[c][i] = *(const float4*)&As[c][ty * 4 + i][kg];
#pragma unroll
        for (int c = 0; c < 2; ++c)
#pragma unroll
          for (int j = 0; j < 4; ++j)
            b4[c][j] = *(const float4*)&Bs[c][tx + 32 * j][kg];
#pragma unroll
        for (int c = 0; c < 2; ++c)
#pragma unroll
          for (int i = 0; i < 4; ++i)
#pragma unroll
            for (int j = 0; j < 4; ++j) {
              acc[c][i][j] += a4[c][i].x * b4[c][j].x;
              acc[c][i][j] += a4[c][i].y * b4[c][j].y;
              acc[c][i][j] += a4[c][i].z * b4[c][j].z;
              acc[c][i][j] += a4[c][i].w * b4[c][j].w;
            }
      }
    }

    // -------- epilogue for this m-chunk --------
    float rim[3][4];
    if (PASS == 2) {
#pragma unroll
      for (int c = 0; c < 3; ++c)
#pragma unroll
        for (int j = 0; j < 4; ++j) {
          int m = m0 + tx + 32 * j;
          rim[c][j] = 1.0f / rsum_g[((size_t)b * 3 + c) * NP + m];
        }
    }
#pragma unroll
    for (int i = 0; i < 4; ++i) {
      int n = n0 + ty * 4 + i;
      int nr = n >> 5, nc = n & 31;
      float s[3][4];
#pragma unroll
      for (int j = 0; j < 4; ++j) {
        int m = m0 + tx + 32 * j;
        int dr = nr - (m >> 5);
        int dc = nc - (m & 31);
        float g = __expf(-(float)(dr * dr + dc * dc) * 0.1953125f);  // 1/5.12 exact
        float wgt = (1.0f - g) * alpha;
        float s0v = acc[0][i][j] * wgt;
        float s1v = acc[1][i][j] * wgt;
        s[0][j] = s0v; s[1][j] = s1v; s[2][j] = 0.5f * (s0v + s1v);
      }
      if (PASS == 1) {
#pragma unroll
        for (int c = 0; c < 3; ++c) {
          sm[c][i] += __expf(s[c][0]) + __expf(s[c][1]) +
                      __expf(s[c][2]) + __expf(s[c][3]);
        }
      } else {
#pragma unroll
        for (int c = 0; c < 3; ++c) {
#pragma unroll
          for (int j = 0; j < 4; ++j) {
            float a = __expf(2.0f * s[c][j]) * rin[c][i] * rim[c][j];
            float n0v = fmaxf(t0[c][i], a);
            float n1v = med3(a, t0[c][i], t1[c][i]);
            float n2v = med3(a, t1[c][i], t2[c][i]);
            t0[c][i] = n0v; t1[c][i] = n1v; t2[c][i] = n2v;
          }
        }
      }
    }
  }

  // -------- cross-lane (32 m-lanes) reduction --------
  if (PASS == 1) {
#pragma unroll
    for (int off = 1; off < 32; off <<= 1) {
#pragma unroll
      for (int c = 0; c < 3; ++c)
#pragma unroll
        for (int i = 0; i < 4; ++i)
          sm[c][i] += __shfl_xor(sm[c][i], off, 64);
    }
    if (tx == 0) {
#pragma unroll
      for (int c = 0; c < 3; ++c)
#pragma unroll
        for (int i = 0; i < 4; ++i) {
          int n = n0 + ty * 4 + i;
          rsum_g[((size_t)b * 3 + c) * NP + n] = sm[c][i];
        }
    }
  } else {
#pragma unroll
    for (int off = 1; off < 32; off <<= 1) {
#pragma unroll
      for (int c = 0; c < 3; ++c)
#pragma unroll
        for (int i = 0; i < 4; ++i) {
          float o0 = __shfl_xor(t0[c][i], off, 64);
          float o1 = __shfl_xor(t1[c][i], off, 64);
          float o2 = __shfl_xor(t2[c][i], off, 64);
          float a0 = t0[c][i], a1 = t1[c][i], a2 = t2[c][i];
          // insert o0
          float b0 = fmaxf(a0, o0), b1 = med3(o0, a0, a1), b2 = med3(o0, a1, a2);
          // insert o1
          float c0 = fmaxf(b0, o1), c1 = med3(o1, b0, b1), c2 = med3(o1, b1, b2);
          // insert o2
          t0[c][i] = fmaxf(c0, o2);
          t1[c][i] = med3(o2, c0, c1);
          t2[c][i] = med3(o2, c1, c2);
        }
    }
    if (tx == 0) {
      // scatter: patch n covers pixels (2nr+pr, 2nc+pc); channel src: p=0->c0, p=3->c1, p=1,2->c2
#pragma unroll
      for (int c = 0; c < 3; ++c)
#pragma unroll
        for (int i = 0; i < 4; ++i) {
          int n = n0 + ty * 4 + i;
          int pr = n >> 5, pc = n & 31;
          float v0 = t0[c][i], v1 = t1[c][i], v2 = t2[c][i];
          int ii0, jj0, ii1 = -1, jj1 = -1;
          if (c == 0)      { ii0 = 2 * pr;     jj0 = 2 * pc; }
          else if (c == 1) { ii0 = 2 * pr + 1; jj0 = 2 * pc + 1; }
          else             { ii0 = 2 * pr;     jj0 = 2 * pc + 1;
                             ii1 = 2 * pr + 1; jj1 = 2 * pc; }
          out[(((size_t)b * 3 + 0) * NH + ii0) * NW + jj0] = v0;
          out[(((size_t)b * 3 + 1) * NH + ii0) * NW + jj0] = v1;
          out[(((size_t)b * 3 + 2) * NH + ii0) * NW + jj0] = v2;
          if (ii1 >= 0) {
            out[(((size_t)b * 3 + 0) * NH + ii1) * NW + jj1] = v0;
            out[(((size_t)b * 3 + 1) * NH + ii1) * NW + jj1] = v1;
            out[(((size_t)b * 3 + 2) * NH + ii1) * NW + jj1] = v2;
          }
        }
    }
  }
}

extern "C" void kernel_launch(void* const* d_in, const int* in_sizes, int n_in,
                              void* d_out, int out_size, void* d_ws, size_t ws_size,
                              hipStream_t stream) {
  const float* x = (const float*)d_in[0];
  const float* alpha = (const float*)d_in[1];
  float* out = (float*)d_out;

  float* V = (float*)d_ws;                                  // 16*2*1024*128 floats = 16 MB
  float* rsum = V + (size_t)NB * 2 * NP * NCH;              // 16*3*1024 floats

  prep_kernel<<<128, 256, 0, stream>>>(x, V);
  corr_kernel<1><<<dim3(NP / TN, NB), 256, 0, stream>>>(V, alpha, rsum, out);
  corr_kernel<2><<<dim3(NP / TN, NB), 256, 0, stream>>>(V, alpha, rsum, out);
}

// Round 3
// 332.167 us; speedup vs baseline: 1.1984x; 1.1984x over previous
//
#include <hip/hip_runtime.h>
#include <math.h>

#define NB 16
#define NCH 128
#define NH 64
#define NW 64
#define NP 1024

#define TN 32    // rows per block
#define TM 128   // m per chunk
#define KC 32    // k chunk (fallback kernels)
#define KP 36    // padded k stride in LDS (fallback)

#define MS 2     // m-split for pass-1 GEMM
#define KC2 16   // k chunk (fast pass 1)
#define KP2 20   // padded k stride (fast pass 1): row stride 80B, 16B-aligned

__device__ __forceinline__ float med3(float a, float b, float c) {
  return __builtin_amdgcn_fmed3f(a, b, c);
}

// insert candidate a into descending top-3 (t0>=t1>=t2)
__device__ __forceinline__ void top3_ins(float& t0, float& t1, float& t2, float a) {
  float n0 = fmaxf(t0, a);
  float n1 = med3(a, t0, t1);
  float n2 = med3(a, t1, t2);
  t0 = n0; t1 = n1; t2 = n2;
}

// ---------------- prep: normalize channel vectors, extract diag-pixel matrices ----------------
// V[b][c][n][ch], c=0 -> pixel (2nr,2nc), c=1 -> (2nr+1,2nc+1)
__global__ __launch_bounds__(256) void prep_kernel(const float* __restrict__ x,
                                                   float* __restrict__ V) {
  int blk = blockIdx.x;            // 0..127
  int t = threadIdx.x;             // 0..255
  int b = blk >> 3;
  int c = (blk >> 2) & 1;
  int n = (blk & 3) * 256 + t;
  int i = 2 * (n >> 5) + c;
  int j = 2 * (n & 31) + c;
  const float* xp = x + (size_t)b * NCH * NH * NW + i * NW + j;
  float ss = 0.f;
#pragma unroll 8
  for (int ch = 0; ch < NCH; ++ch) {
    float v = xp[(size_t)ch * NH * NW];
    ss += v * v;
  }
  float r = 1.0f / fmaxf(sqrtf(ss), 1e-12f);
  float* vp = V + (((size_t)b * 2 + c) * NP + n) * NCH;
#pragma unroll 8
  for (int ch = 0; ch < NCH; ++ch) {
    vp[ch] = xp[(size_t)ch * NH * NW] * r;
  }
}

// ================= FAST PATH =================
// pass 1: GEMM over half the m-range; store s (2 channels) to Sbuf; partial exp-sums.
__global__ __launch_bounds__(256, 4) void gemm_pass1(
    const float* __restrict__ V, const float* __restrict__ alpha_p,
    float* __restrict__ rsum_part, float2* __restrict__ Sbuf) {
  __shared__ __align__(16) float As[2][TN][KP2];
  __shared__ __align__(16) float Bs[2][TM][KP2];

  const int b = blockIdx.y;
  const int n0 = (blockIdx.x >> 1) * TN;
  const int half = blockIdx.x & 1;
  const int t = threadIdx.x;
  const int tx = t & 31;   // m-slot: m = m0 + tx + 32*j
  const int ty = t >> 5;   // row group: rows n0 + ty*4 + i
  const float alpha = *alpha_p;
  const float* Vb = V + (size_t)b * 2 * NP * NCH;

  float sm[3][4];
#pragma unroll
  for (int c = 0; c < 3; ++c)
#pragma unroll
    for (int i = 0; i < 4; ++i) sm[c][i] = 0.f;

  for (int mc = half * 4; mc < half * 4 + 4; ++mc) {
    const int m0 = mc * TM;
    float acc[2][4][4];
#pragma unroll
    for (int c = 0; c < 2; ++c)
#pragma unroll
      for (int i = 0; i < 4; ++i)
#pragma unroll
        for (int j = 0; j < 4; ++j) acc[c][i][j] = 0.f;

    for (int k0 = 0; k0 < NCH; k0 += KC2) {
      __syncthreads();
      // A tile: 2*32*16 floats = 256 float4 -> 1 per thread
      {
        int c = t >> 7;
        int rem = t & 127;
        int row = rem >> 2;
        int kg = rem & 3;
        float4 v4 = *(const float4*)(Vb + ((size_t)c * NP + n0 + row) * NCH + k0 + kg * 4);
        *(float4*)&As[c][row][kg * 4] = v4;
      }
      // B tile: 2*128*16 floats = 1024 float4 -> 4 per thread
#pragma unroll
      for (int q = 0; q < 4; ++q) {
        int flat = q * 256 + t;
        int c = flat >> 9;
        int rem = flat & 511;
        int row = rem >> 2;
        int kg = rem & 3;
        float4 v4 = *(const float4*)(Vb + ((size_t)c * NP + m0 + row) * NCH + k0 + kg * 4);
        *(float4*)&Bs[c][row][kg * 4] = v4;
      }
      __syncthreads();

#pragma unroll
      for (int kg = 0; kg < KC2; kg += 4) {
        float4 a4[2][4], b4[2][4];
#pragma unroll
        for (int c = 0; c < 2; ++c)
#pragma unroll
          for (int i = 0; i < 4; ++i)
            a4[c][i] = *(const float4*)&As[c][ty * 4 + i][kg];
#pragma unroll
        for (int c = 0; c < 2; ++c)
#pragma unroll
          for (int j = 0; j < 4; ++j)
            b4[c][j] = *(const float4*)&Bs[c][tx + 32 * j][kg];
#pragma unroll
        for (int c = 0; c < 2; ++c)
#pragma unroll
          for (int i = 0; i < 4; ++i)
#pragma unroll
            for (int j = 0; j < 4; ++j) {
              acc[c][i][j] += a4[c][i].x * b4[c][j].x;
              acc[c][i][j] += a4[c][i].y * b4[c][j].y;
              acc[c][i][j] += a4[c][i].z * b4[c][j].z;
              acc[c][i][j] += a4[c][i].w * b4[c][j].w;
            }
      }
    }

    // epilogue: mask*alpha, store s, accumulate exp-sums
#pragma unroll
    for (int i = 0; i < 4; ++i) {
      int n = n0 + ty * 4 + i;
      int nr = n >> 5, nc = n & 31;
      float2* rowp = Sbuf + ((size_t)b * NP + n) * NP;
#pragma unroll
      for (int j = 0; j < 4; ++j) {
        int m = m0 + tx + 32 * j;
        int dr = nr - (m >> 5);
        int dc = nc - (m & 31);
        float g = __expf(-(float)(dr * dr + dc * dc) * 0.1953125f);  // 1/5.12 exact
        float wgt = (1.0f - g) * alpha;
        float s0v = acc[0][i][j] * wgt;
        float s1v = acc[1][i][j] * wgt;
        rowp[m] = make_float2(s0v, s1v);
        float s2v = 0.5f * (s0v + s1v);
        sm[0][i] += __expf(s0v);
        sm[1][i] += __expf(s1v);
        sm[2][i] += __expf(s2v);
      }
    }
  }

  // reduce partial sums across the 32 m-lanes
#pragma unroll
  for (int off = 1; off < 32; off <<= 1) {
#pragma unroll
    for (int c = 0; c < 3; ++c)
#pragma unroll
      for (int i = 0; i < 4; ++i)
        sm[c][i] += __shfl_xor(sm[c][i], off, 64);
  }
  if (tx == 0) {
#pragma unroll
    for (int c = 0; c < 3; ++c)
#pragma unroll
      for (int i = 0; i < 4; ++i) {
        int n = n0 + ty * 4 + i;
        rsum_part[(((size_t)b * MS + half) * 3 + c) * NP + n] = sm[c][i];
      }
  }
}

// sum the m-half partials, store reciprocal
__global__ __launch_bounds__(256) void finalize_rsum(const float* __restrict__ part,
                                                     float* __restrict__ rinv) {
  int i = blockIdx.x * 256 + threadIdx.x;  // i < NB*3*NP
  int n = i & (NP - 1);
  int bc = i >> 10;
  int b = bc / 3, c = bc - 3 * b;
  float s = part[(((size_t)b * MS + 0) * 3 + c) * NP + n] +
            part[(((size_t)b * MS + 1) * 3 + c) * NP + n];
  rinv[i] = 1.0f / s;
}

// pass 2: one block per (b, n-row): read s, A=exp(2s)*rinv_n*rinv_m, top-3, scatter.
__global__ __launch_bounds__(256, 4) void topk_kernel(
    const float2* __restrict__ Sbuf, const float* __restrict__ rinv,
    float* __restrict__ out) {
  const int n = blockIdx.x, b = blockIdx.y;
  const int t = threadIdx.x;
  const float* rb = rinv + (size_t)b * 3 * NP;
  float rin[3];
#pragma unroll
  for (int c = 0; c < 3; ++c) rin[c] = rb[c * NP + n];
  const float2* row = Sbuf + ((size_t)b * NP + n) * NP;

  float t0[3] = {0.f, 0.f, 0.f}, t1[3] = {0.f, 0.f, 0.f}, t2[3] = {0.f, 0.f, 0.f};
#pragma unroll
  for (int q = 0; q < 4; ++q) {
    int m = t + q * 256;
    float2 s01 = row[m];
    float s[3];
    s[0] = s01.x; s[1] = s01.y; s[2] = 0.5f * (s01.x + s01.y);
#pragma unroll
    for (int c = 0; c < 3; ++c) {
      float a = __expf(2.0f * s[c]) * rin[c] * rb[c * NP + m];
      top3_ins(t0[c], t1[c], t2[c], a);
    }
  }
  // 64-lane butterfly merge
#pragma unroll
  for (int off = 1; off < 64; off <<= 1) {
#pragma unroll
    for (int c = 0; c < 3; ++c) {
      float o0 = __shfl_xor(t0[c], off, 64);
      float o1 = __shfl_xor(t1[c], off, 64);
      float o2 = __shfl_xor(t2[c], off, 64);
      top3_ins(t0[c], t1[c], t2[c], o0);
      top3_ins(t0[c], t1[c], t2[c], o1);
      top3_ins(t0[c], t1[c], t2[c], o2);
    }
  }
  __shared__ float lds[4][9];
  if ((t & 63) == 0) {
    int w = t >> 6;
#pragma unroll
    for (int c = 0; c < 3; ++c) {
      lds[w][c * 3 + 0] = t0[c];
      lds[w][c * 3 + 1] = t1[c];
      lds[w][c * 3 + 2] = t2[c];
    }
  }
  __syncthreads();
  if (t == 0) {
#pragma unroll
    for (int w = 1; w < 4; ++w)
#pragma unroll
      for (int c = 0; c < 3; ++c) {
        top3_ins(t0[c], t1[c], t2[c], lds[w][c * 3 + 0]);
        top3_ins(t0[c], t1[c], t2[c], lds[w][c * 3 + 1]);
        top3_ins(t0[c], t1[c], t2[c], lds[w][c * 3 + 2]);
      }
    int pr = n >> 5, pc = n & 31;
#pragma unroll
    for (int c = 0; c < 3; ++c) {
      int ii0, jj0, ii1 = -1, jj1 = -1;
      if (c == 0)      { ii0 = 2 * pr;     jj0 = 2 * pc; }
      else if (c == 1) { ii0 = 2 * pr + 1; jj0 = 2 * pc + 1; }
      else             { ii0 = 2 * pr;     jj0 = 2 * pc + 1;
                         ii1 = 2 * pr + 1; jj1 = 2 * pc; }
      out[(((size_t)b * 3 + 0) * NH + ii0) * NW + jj0] = t0[c];
      out[(((size_t)b * 3 + 1) * NH + ii0) * NW + jj0] = t1[c];
      out[(((size_t)b * 3 + 2) * NH + ii0) * NW + jj0] = t2[c];
      if (ii1 >= 0) {
        out[(((size_t)b * 3 + 0) * NH + ii1) * NW + jj1] = t0[c];
        out[(((size_t)b * 3 + 1) * NH + ii1) * NW + jj1] = t1[c];
        out[(((size_t)b * 3 + 2) * NH + ii1) * NW + jj1] = t2[c];
      }
    }
  }
}

// ================= FALLBACK PATH (round-1 kernels, unchanged) =================
template <int PASS>
__global__ __launch_bounds__(256, 2) void corr_kernel(
    const float* __restrict__ V, const float* __restrict__ alpha_p,
    float* __restrict__ rsum_g, float* __restrict__ out) {
  __shared__ __align__(16) float As[2][TN][KP];
  __shared__ __align__(16) float Bs[2][TM][KP];

  const int b = blockIdx.y;
  const int n0 = blockIdx.x * TN;
  const int t = threadIdx.x;
  const int tx = t & 31;
  const int ty = t >> 5;
  const float alpha = *alpha_p;
  const float* Vb = V + (size_t)b * 2 * NP * NCH;

  float sm[3][4];
  float t0[3][4], t1[3][4], t2[3][4];
  float rin[3][4];
#pragma unroll
  for (int c = 0; c < 3; ++c)
#pragma unroll
    for (int i = 0; i < 4; ++i) {
      sm[c][i] = 0.f;
      t0[c][i] = 0.f; t1[c][i] = 0.f; t2[c][i] = 0.f;
    }
  if (PASS == 2) {
#pragma unroll
    for (int c = 0; c < 3; ++c)
#pragma unroll
      for (int i = 0; i < 4; ++i) {
        int n = n0 + ty * 4 + i;
        rin[c][i] = 1.0f / rsum_g[((size_t)b * 3 + c) * NP + n];
      }
  }

  for (int mc = 0; mc < NP / TM; ++mc) {
    const int m0 = mc * TM;
    float acc[2][4][4];
#pragma unroll
    for (int c = 0; c < 2; ++c)
#pragma unroll
      for (int i = 0; i < 4; ++i)
#pragma unroll
        for (int j = 0; j < 4; ++j) acc[c][i][j] = 0.f;

    for (int k0 = 0; k0 < NCH; k0 += KC) {
      __syncthreads();
#pragma unroll
      for (int q = 0; q < 2; ++q) {
        int flat = q * 256 + t;
        int c = flat >> 8;
        int rem = flat & 255;
        int row = rem >> 3;
        int kg = rem & 7;
        float4 v4 = *(const float4*)(Vb + ((size_t)c * NP + n0 + row) * NCH + k0 + kg * 4);
        *(float4*)&As[c][row][kg * 4] = v4;
      }
#pragma unroll
      for (int q = 0; q < 8; ++q) {
        int flat = q * 256 + t;
        int c = flat >> 10;
        int rem = flat & 1023;
        int row = rem >> 3;
        int kg = rem & 7;
        float4 v4 = *(const float4*)(Vb + ((size_t)c * NP + m0 + row) * NCH + k0 + kg * 4);
        *(float4*)&Bs[c][row][kg * 4] = v4;
      }
      __syncthreads();

      for (int kg = 0; kg < KC; kg += 4) {
        float4 a4[2][4], b4[2][4];
#pragma unroll
        for (int c = 0; c < 2; ++c)
#pragma unroll
          for (int i = 0; i < 4; ++i)
            a4[c][i] = *(const float4*)&As[c][ty * 4 + i][kg];
#pragma unroll
        for (int c = 0; c < 2; ++c)
#pragma unroll
          for (int j = 0; j < 4; ++j)
            b4[c][j] = *(const float4*)&Bs[c][tx + 32 * j][kg];
#pragma unroll
        for (int c = 0; c < 2; ++c)
#pragma unroll
          for (int i = 0; i < 4; ++i)
#pragma unroll
            for (int j = 0; j < 4; ++j) {
              acc[c][i][j] += a4[c][i].x * b4[c][j].x;
              acc[c][i][j] += a4[c][i].y * b4[c][j].y;
              acc[c][i][j] += a4[c][i].z * b4[c][j].z;
              acc[c][i][j] += a4[c][i].w * b4[c][j].w;
            }
      }
    }

    float rim[3][4];
    if (PASS == 2) {
#pragma unroll
      for (int c = 0; c < 3; ++c)
#pragma unroll
        for (int j = 0; j < 4; ++j) {
          int m = m0 + tx + 32 * j;
          rim[c][j] = 1.0f / rsum_g[((size_t)b * 3 + c) * NP + m];
        }
    }
#pragma unroll
    for (int i = 0; i < 4; ++i) {
      int n = n0 + ty * 4 + i;
      int nr = n >> 5, nc = n & 31;
      float s[3][4];
#pragma unroll
      for (int j = 0; j < 4; ++j) {
        int m = m0 + tx + 32 * j;
        int dr = nr - (m >> 5);
        int dc = nc - (m & 31);
        float g = __expf(-(float)(dr * dr + dc * dc) * 0.1953125f);
        float wgt = (1.0f - g) * alpha;
        float s0v = acc[0][i][j] * wgt;
        float s1v = acc[1][i][j] * wgt;
        s[0][j] = s0v; s[1][j] = s1v; s[2][j] = 0.5f * (s0v + s1v);
      }
      if (PASS == 1) {
#pragma unroll
        for (int c = 0; c < 3; ++c) {
          sm[c][i] += __expf(s[c][0]) + __expf(s[c][1]) +
                      __expf(s[c][2]) + __expf(s[c][3]);
        }
      } else {
#pragma unroll
        for (int c = 0; c < 3; ++c) {
#pragma unroll
          for (int j = 0; j < 4; ++j) {
            float a = __expf(2.0f * s[c][j]) * rin[c][i] * rim[c][j];
            top3_ins(t0[c][i], t1[c][i], t2[c][i], a);
          }
        }
      }
    }
  }

  if (PASS == 1) {
#pragma unroll
    for (int off = 1; off < 32; off <<= 1) {
#pragma unroll
      for (int c = 0; c < 3; ++c)
#pragma unroll
        for (int i = 0; i < 4; ++i)
          sm[c][i] += __shfl_xor(sm[c][i], off, 64);
    }
    if (tx == 0) {
#pragma unroll
      for (int c = 0; c < 3; ++c)
#pragma unroll
        for (int i = 0; i < 4; ++i) {
          int n = n0 + ty * 4 + i;
          rsum_g[((size_t)b * 3 + c) * NP + n] = sm[c][i];
        }
    }
  } else {
#pragma unroll
    for (int off = 1; off < 32; off <<= 1) {
#pragma unroll
      for (int c = 0; c < 3; ++c)
#pragma unroll
        for (int i = 0; i < 4; ++i) {
          float o0 = __shfl_xor(t0[c][i], off, 64);
          float o1 = __shfl_xor(t1[c][i], off, 64);
          float o2 = __shfl_xor(t2[c][i], off, 64);
          top3_ins(t0[c][i], t1[c][i], t2[c][i], o0);
          top3_ins(t0[c][i], t1[c][i], t2[c][i], o1);
          top3_ins(t0[c][i], t1[c][i], t2[c][i], o2);
        }
    }
    if (tx == 0) {
#pragma unroll
      for (int c = 0; c < 3; ++c)
#pragma unroll
        for (int i = 0; i < 4; ++i) {
          int n = n0 + ty * 4 + i;
          int pr = n >> 5, pc = n & 31;
          float v0 = t0[c][i], v1 = t1[c][i], v2 = t2[c][i];
          int ii0, jj0, ii1 = -1, jj1 = -1;
          if (c == 0)      { ii0 = 2 * pr;     jj0 = 2 * pc; }
          else if (c == 1) { ii0 = 2 * pr + 1; jj0 = 2 * pc + 1; }
          else             { ii0 = 2 * pr;     jj0 = 2 * pc + 1;
                             ii1 = 2 * pr + 1; jj1 = 2 * pc; }
          out[(((size_t)b * 3 + 0) * NH + ii0) * NW + jj0] = v0;
          out[(((size_t)b * 3 + 1) * NH + ii0) * NW + jj0] = v1;
          out[(((size_t)b * 3 + 2) * NH + ii0) * NW + jj0] = v2;
          if (ii1 >= 0) {
            out[(((size_t)b * 3 + 0) * NH + ii1) * NW + jj1] = v0;
            out[(((size_t)b * 3 + 1) * NH + ii1) * NW + jj1] = v1;
            out[(((size_t)b * 3 + 2) * NH + ii1) * NW + jj1] = v2;
          }
        }
    }
  }
}

extern "C" void kernel_launch(void* const* d_in, const int* in_sizes, int n_in,
                              void* d_out, int out_size, void* d_ws, size_t ws_size,
                              hipStream_t stream) {
  const float* x = (const float*)d_in[0];
  const float* alpha = (const float*)d_in[1];
  float* out = (float*)d_out;

  // workspace layout (floats)
  const size_t nV = (size_t)NB * 2 * NP * NCH;      // 4,194,304
  const size_t nPart = (size_t)NB * MS * 3 * NP;    // 98,304
  const size_t nRs = (size_t)NB * 3 * NP;           // 49,152
  const size_t nS = (size_t)NB * NP * NP;           // 16,777,216 float2 slots

  float* V = (float*)d_ws;
  float* rsum_part = V + nV;
  float* rinv = rsum_part + nPart;
  float2* Sbuf = (float2*)(rinv + nRs);

  const size_t need_bytes = (nV + nPart + nRs) * 4 + nS * 8;

  prep_kernel<<<128, 256, 0, stream>>>(x, V);

  if (ws_size >= need_bytes) {
    gemm_pass1<<<dim3((NP / TN) * MS, NB), 256, 0, stream>>>(V, alpha, rsum_part, Sbuf);
    finalize_rsum<<<(NB * 3 * NP) / 256, 256, 0, stream>>>(rsum_part, rinv);
    topk_kernel<<<dim3(NP, NB), 256, 0, stream>>>(Sbuf, rinv, out);
  } else {
    float* rsum = rsum_part;  // reuse as full sums
    corr_kernel<1><<<dim3(NP / TN, NB), 256, 0, stream>>>(V, alpha, rsum, out);
    corr_kernel<2><<<dim3(NP / TN, NB), 256, 0, stream>>>(V, alpha, rsum, out);
  }
}